// Round 1
// baseline (156.968 us; speedup 1.0000x reference)
//
#include <hip/hip_runtime.h>
#include <math.h>

#define NB 8            // batch
#define NPIX 262144     // 512*512
#define NBINS 2048      // level-1 bins (bits >> 21)
#define NBINS2 256      // level-2 sub-bins (bits >> 13 & 255)
#define TPB 256
#define TPB2 512        // pass-2 block size
#define BPS 64          // blocks per sample (pass 1)
#define PPB (NPIX / BPS)   // 4096 pixels per block
#define BPU2 16         // pass-2 blocks per unit
#define CPB2 (NPIX / BPU2) // 16384 values per pass-2 block
#define EPS2 1e-12f

struct SelState { unsigned b1; unsigned rem; unsigned k; unsigned pad; };

#define F4E(v,j) (((const float*)&(v))[j])
#define I4E(v,j) (((const int*)&(v))[j])

__device__ __forceinline__ void pixel_vals(float a, float p,
                                           float i0, float i1, float i2,
                                           float f0, float f1, float f2,
                                           float g0, float g1, float g2,
                                           float& d, float& dc)
{
    float diff = a * (1.0f / 255.0f) - p;
    d = sqrtf(diff * diff + EPS2);
    float om = 1.0f - p;
    float e0 = i0 - (f0 * p + om * g0);
    float e1 = i1 - (f1 * p + om * g1);
    float e2 = i2 - (f2 * p + om * g2);
    dc = sqrtf(e0 * e0 + EPS2) + sqrtf(e1 * e1 + EPS2) + sqrtf(e2 * e2 + EPS2);
}

// ---------------- Pass 1: compute values, store them, count-only level-1 histogram ----------------
__global__ __launch_bounds__(TPB) void k_pass1(
    const float* __restrict__ image, const float* __restrict__ alpha,
    const float* __restrict__ pred, const int* __restrict__ trimap,
    const float* __restrict__ fg, const float* __restrict__ bg,
    unsigned* __restrict__ gcnt, unsigned* __restrict__ h1c, float* __restrict__ vals)
{
    __shared__ unsigned hc[2 * NBINS];   // counts only: [0..NBINS) = d, [NBINS..2N) = dc
    const int tid = threadIdx.x;
    for (int i = tid; i < 2 * NBINS; i += TPB) hc[i] = 0u;
    __syncthreads();

    const int s = blockIdx.x / BPS;
    const int chunk = blockIdx.x % BPS;
    const int pbase = s * NPIX + chunk * PPB;
    const int cbase = s * 3 * NPIX + chunk * PPB;
    // unit-major value layout: unit = s*2 + {0:d, 1:dc}
    float* vd = vals + (s * 2 + 0) * NPIX + chunk * PPB;
    float* vc = vals + (s * 2 + 1) * NPIX + chunk * PPB;

    const float md  = sqrtf(EPS2);        // masked-pixel d value
    const float mdc = md + md + md;       // masked-pixel dc value

    unsigned nUnk = 0, nMask = 0;

    for (int it = 0; it < PPB / (TPB * 4); ++it) {
        const int off = (it * TPB + tid) * 4;
        int4   tm = *(const int4*)(trimap + pbase + off);
        float4 al = *(const float4*)(alpha + pbase + off);
        float4 pr = *(const float4*)(pred + pbase + off);
        float4 i0 = *(const float4*)(image + cbase + off);
        float4 i1 = *(const float4*)(image + cbase + NPIX + off);
        float4 i2 = *(const float4*)(image + cbase + 2 * NPIX + off);
        float4 f0 = *(const float4*)(fg + cbase + off);
        float4 f1 = *(const float4*)(fg + cbase + NPIX + off);
        float4 f2 = *(const float4*)(fg + cbase + 2 * NPIX + off);
        float4 g0 = *(const float4*)(bg + cbase + off);
        float4 g1 = *(const float4*)(bg + cbase + NPIX + off);
        float4 g2 = *(const float4*)(bg + cbase + 2 * NPIX + off);
        float4 od, oc;
#pragma unroll
        for (int j = 0; j < 4; ++j) {
            float d, dc;
            if (I4E(tm, j) == 128) {
                ++nUnk;
                pixel_vals(F4E(al, j), F4E(pr, j),
                           F4E(i0, j), F4E(i1, j), F4E(i2, j),
                           F4E(f0, j), F4E(f1, j), F4E(f2, j),
                           F4E(g0, j), F4E(g1, j), F4E(g2, j), d, dc);
                atomicAdd(&hc[__float_as_uint(d) >> 21], 1u);
                atomicAdd(&hc[NBINS + (__float_as_uint(dc) >> 21)], 1u);
            } else {
                ++nMask;
                d = md; dc = mdc;
            }
            ((float*)&od)[j] = d;
            ((float*)&oc)[j] = dc;
        }
        *(float4*)(vd + off) = od;
        *(float4*)(vc + off) = oc;
    }

    // reduce per-thread counters: wave shuffle then LDS
    unsigned u = nUnk, m = nMask;
#pragma unroll
    for (int o = 32; o > 0; o >>= 1) { u += __shfl_down(u, o); m += __shfl_down(m, o); }
    __shared__ unsigned wred[8];
    const int wave = tid >> 6;
    if ((tid & 63) == 0) { wred[wave * 2] = u; wred[wave * 2 + 1] = m; }
    __syncthreads();
    if (tid == 0) {
        unsigned U = 0, M = 0;
        for (int w = 0; w < 4; ++w) { U += wred[w * 2]; M += wred[w * 2 + 1]; }
        atomicAdd(&gcnt[s], U);
        if (M) {  // all masked pixels hit one known bin per array: one aggregated update
            atomicAdd(&hc[__float_as_uint(md) >> 21], M);
            atomicAdd(&hc[NBINS + (__float_as_uint(mdc) >> 21)], M);
        }
    }
    __syncthreads();

    for (int i = tid; i < 2 * NBINS; i += TPB) {
        unsigned c = hc[i];
        if (c) {
            int arr = (i >= NBINS) ? 1 : 0;
            int b = i & (NBINS - 1);
            atomicAdd(&h1c[(s * 2 + arr) * NBINS + b], c);
        }
    }
}

// ---------------- Level-1 selection (counts only) ----------------
__global__ __launch_bounds__(TPB) void k_select1(
    const unsigned* __restrict__ gcnt, const unsigned* __restrict__ h1c,
    SelState* __restrict__ st)
{
    const int unit = blockIdx.x;
    const int s = unit >> 1;
    const int t = threadIdx.x;
    const unsigned* hc = h1c + unit * NBINS;
    unsigned count = gcnt[s];
    int k = (int)floorf((float)count * 0.7f);

    __shared__ unsigned spc[TPB];
    unsigned pc = 0;
#pragma unroll
    for (int j = 0; j < NBINS / TPB; ++j) pc += hc[t * (NBINS / TPB) + j];
    spc[t] = pc;
    __syncthreads();
    __shared__ unsigned sufc[TPB + 1];
    if (t == 0) {
        unsigned c = 0;
        sufc[TPB] = 0;
        for (int i = TPB - 1; i >= 0; --i) { c += spc[i]; sufc[i] = c; }
    }
    __syncthreads();
    if (k <= 0) {
        if (t == 0) { st[unit].b1 = 0xFFFFFFFFu; st[unit].rem = 0; st[unit].k = 0; }
        return;
    }
    unsigned above = sufc[t + 1];
    if (above < (unsigned)k && (unsigned)k <= sufc[t]) {
        unsigned c = above;
        int b1 = t * (NBINS / TPB);
        for (int j = NBINS / TPB - 1; j >= 0; --j) {
            unsigned bcn = hc[t * (NBINS / TPB) + j];
            if (c + bcn >= (unsigned)k) { b1 = t * (NBINS / TPB) + j; break; }
            c += bcn;
        }
        st[unit].b1 = (unsigned)b1;
        st[unit].rem = (unsigned)k - c;   // >= 1
        st[unit].k = (unsigned)k;
    }
}

// ---------------- Pass 2: sum above b1; LDS level-2 hist for bin == b1; private hist store ----------------
__global__ __launch_bounds__(TPB2) void k_pass2(
    const float* __restrict__ vals, const SelState* __restrict__ st,
    float* __restrict__ hpriv, float* __restrict__ sumgt)
{
    const int unit = blockIdx.x >> 4;     // BPU2 = 16 blocks per unit
    const int chunk = blockIdx.x & (BPU2 - 1);
    const SelState S = st[unit];
    if (S.b1 == 0xFFFFFFFFu) return;      // uniform early exit, before any barrier

    __shared__ unsigned hcnt[NBINS2];
    __shared__ float    hsum[NBINS2];
    const int tid = threadIdx.x;
    if (tid < NBINS2) { hcnt[tid] = 0u; hsum[tid] = 0.f; }
    __syncthreads();

    const float* v = vals + unit * NPIX + chunk * CPB2;
    float lsum = 0.f;
#pragma unroll
    for (int it = 0; it < CPB2 / (TPB2 * 4); ++it) {
        const int off = (it * TPB2 + tid) * 4;
        float4 x = *(const float4*)(v + off);
#pragma unroll
        for (int j = 0; j < 4; ++j) {
            float val = F4E(x, j);
            unsigned bits = __float_as_uint(val);
            unsigned b = bits >> 21;
            if (b > S.b1) {
                lsum += val;
            } else if (b == S.b1) {
                unsigned sb = (bits >> 13) & (NBINS2 - 1);
                atomicAdd(&hcnt[sb], 1u);      // LDS atomics only
                atomicAdd(&hsum[sb], val);
            }
        }
    }
    // block-reduce lsum
#pragma unroll
    for (int o = 32; o > 0; o >>= 1) lsum += __shfl_down(lsum, o);
    __shared__ float wred[TPB2 / 64];
    const int wave = tid >> 6;
    if ((tid & 63) == 0) wred[wave] = lsum;
    __syncthreads();   // also orders all LDS hist atomics before the flush below
    if (tid == 0) {
        float tot = 0.f;
        for (int w = 0; w < TPB2 / 64; ++w) tot += wred[w];
        atomicAdd(&sumgt[unit], tot);
    }
    // flush private histogram with plain stores (counts exact as floats, <= 16384)
    float* outp = hpriv + (size_t)(unit * BPU2 + chunk) * (2 * NBINS2);
    if (tid < NBINS2) {
        outp[tid] = (float)hcnt[tid];
        outp[NBINS2 + tid] = hsum[tid];
    }
}

// ---------------- Level-2 selection + final combine (atomic into zeroed d_out) ----------------
__global__ __launch_bounds__(TPB) void k_select2_final(
    const float* __restrict__ hpriv, const SelState* __restrict__ st,
    const float* __restrict__ sumgt, float* __restrict__ out)
{
    const int unit = blockIdx.x;
    const int t = threadIdx.x;          // TPB == NBINS2: thread t owns sub-bin t
    const SelState S = st[unit];
    if (S.b1 == 0xFFFFFFFFu) return;    // k==0 contributes 0

    __shared__ unsigned cnt[NBINS2];
    __shared__ float    sm[NBINS2];
    float c = 0.f, s = 0.f;
    const float* base = hpriv + (size_t)unit * BPU2 * (2 * NBINS2);
    for (int ch = 0; ch < BPU2; ++ch) {
        c += base[ch * (2 * NBINS2) + t];
        s += base[ch * (2 * NBINS2) + NBINS2 + t];
    }
    cnt[t] = (unsigned)c;               // exact: integral floats <= 262144
    sm[t]  = s;
    __syncthreads();
    __shared__ unsigned sufc[NBINS2 + 1];
    __shared__ float    sufs[NBINS2 + 1];
    if (t == 0) {
        unsigned cc = 0; float ss = 0.f;
        sufc[NBINS2] = 0; sufs[NBINS2] = 0.f;
        for (int i = NBINS2 - 1; i >= 0; --i) { cc += cnt[i]; ss += sm[i]; sufc[i] = cc; sufs[i] = ss; }
    }
    __syncthreads();
    unsigned k = S.rem;                 // >= 1, guaranteed <= total count in bin b1
    unsigned above = sufc[t + 1];
    if (above < k && k <= sufc[t]) {
        unsigned rem2 = k - above;
        float avg = sm[t] / (float)cnt[t];   // sub-bin width ~2^-8 of a level-1 bin -> negligible error
        float sum_k = sumgt[unit] + sufs[t + 1] + (float)rem2 * avg;
        float loss = sum_k / ((float)S.k + 1e-6f);
        atomicAdd(out, 0.0625f * loss);      // 0.5 stage weight / 8 samples, both arrays
    }
}

extern "C" void kernel_launch(void* const* d_in, const int* in_sizes, int n_in,
                              void* d_out, int out_size, void* d_ws, size_t ws_size,
                              hipStream_t stream)
{
    const float* image  = (const float*)d_in[0];
    const float* alpha  = (const float*)d_in[1];
    const float* pred   = (const float*)d_in[2];
    const int*   trimap = (const int*)d_in[3];
    const float* fg     = (const float*)d_in[4];
    const float* bg     = (const float*)d_in[5];
    float* out = (float*)d_out;

    char* ws = (char*)d_ws;
    // layout: gcnt[8](64B) | h1c 128KB | sumgt[16](64B) | st[16](256B) | pad | vals 16MB | hpriv 512KB
    unsigned* gcnt = (unsigned*)(ws);
    unsigned* h1c  = (unsigned*)(ws + 64);
    float*    sumgt= (float*)(ws + 64 + 131072);
    SelState* st   = (SelState*)(ws + 64 + 131072 + 64);
    float*    vals = (float*)(ws + 262144);
    float*    hpriv= (float*)(ws + 262144 + (size_t)NB * 2 * NPIX * 4);
    const size_t zbytes = 64 + 131072 + 64;   // gcnt..sumgt (st fully written by k_select1)

    hipMemsetAsync(d_ws, 0, zbytes, stream);
    hipMemsetAsync(d_out, 0, sizeof(float), stream);
    k_pass1<<<NB * BPS, TPB, 0, stream>>>(image, alpha, pred, trimap, fg, bg, gcnt, h1c, vals);
    k_select1<<<NB * 2, TPB, 0, stream>>>(gcnt, h1c, st);
    k_pass2<<<NB * 2 * BPU2, TPB2, 0, stream>>>(vals, st, hpriv, sumgt);
    k_select2_final<<<NB * 2, TPB, 0, stream>>>(hpriv, st, sumgt, out);
}